// Round 7
// baseline (103.358 us; speedup 1.0000x reference)
//
#include <hip/hip_runtime.h>

#define N 4096
#define F 64
#define BZ 4
#define NC 65            // 64 features + 1 denominator component
// hierarchy: 64 superchunks x 16 subchunks x 4 rows = 4096 sorted rows

// order-preserving float <-> uint32 mapping (order- and equality-isomorphic)
__device__ __forceinline__ unsigned int f2ord(float f) {
    unsigned int u = __float_as_uint(f);
    return (u & 0x80000000u) ? ~u : (u ^ 0x80000000u);
}
__device__ __forceinline__ float ord2f(unsigned int v) {
    unsigned int b = (v & 0x80000000u) ? (v ^ 0x80000000u) : ~v;
    return __uint_as_float(b);
}

// ---------------------------------------------------------------------------
// K1: karr[b][i] = x·wk (float); qord[b][i] = ord(x·wq) (u32). Wave per row.
// ---------------------------------------------------------------------------
__global__ __launch_bounds__(256) void kq_kernel(
        const float* __restrict__ x, const float* __restrict__ wk,
        const float* __restrict__ wq, float* __restrict__ karr,
        unsigned int* __restrict__ qord) {
    int wave = blockIdx.x * 4 + (threadIdx.x >> 6);
    int lane = threadIdx.x & 63;
    int row = wave;                     // 0..BZ*N-1
    float xv = x[(size_t)row * F + lane];
    float kk = xv * wk[lane];
    float qq = xv * wq[lane];
    for (int off = 32; off > 0; off >>= 1) {
        kk += __shfl_down(kk, off, 64);
        qq += __shfl_down(qq, off, 64);
    }
    if (lane == 0) {
        karr[row] = kk;
        qord[row] = f2ord(qq);
    }
}

// ---------------------------------------------------------------------------
// K2: counting rank-sort on u32 ord keys + split points + x permutation.
// grid BZ*64 x 1024. uint4 broadcast LDS reads: 1024 ds_read_b128 per block
// (half of the u64-key version -> ~5 us LDS pipe). Tie-break in VALU:
//   rank_j = #{s : q_s < q_j || (q_s == q_j && s < j)}   (exact permutation)
//   p_j    = #{s : ord(q_s) < ord(-k_j)}  (tie direction irrelevant: e^0 both)
// ---------------------------------------------------------------------------
__global__ __launch_bounds__(1024) void rank_kernel(
        const float* __restrict__ x, const float* __restrict__ karr,
        const unsigned int* __restrict__ qord,
        float* __restrict__ q_sorted, int* __restrict__ p_arr,
        float* __restrict__ xs) {
    __shared__ __align__(16) unsigned int qs[N];         // 16 KB
    __shared__ unsigned short pc[16][64];
    __shared__ unsigned short pc2[16][64];
    __shared__ unsigned short rs[64];
    int b = blockIdx.x >> 6;
    int tid = threadIdx.x;
    int wave = tid >> 6, lane = tid & 63;
    const unsigned int* qb = qord + b * N;
    for (int t = tid; t < N; t += 1024) qs[t] = qb[t];
    __syncthreads();

    int jbase = (blockIdx.x & 63) * 64;
    int j = jbase + lane;
    unsigned int qj = qs[j];
    unsigned int thOu = f2ord(-karr[b * N + j]);
    int cnt = 0, cnt2 = 0;
    const uint4* q4 = (const uint4*)qs;
    int s0 = wave * 64;                       // uint4 units
#pragma unroll 8
    for (int t4 = 0; t4 < 64; ++t4) {
        uint4 v = q4[s0 + t4];
        int sb = (s0 + t4) * 4;
        cnt  += (int)((v.x < qj) | ((v.x == qj) & (sb + 0 < j)));
        cnt  += (int)((v.y < qj) | ((v.y == qj) & (sb + 1 < j)));
        cnt  += (int)((v.z < qj) | ((v.z == qj) & (sb + 2 < j)));
        cnt  += (int)((v.w < qj) | ((v.w == qj) & (sb + 3 < j)));
        cnt2 += (int)(v.x < thOu) + (int)(v.y < thOu)
              + (int)(v.z < thOu) + (int)(v.w < thOu);
    }
    pc[wave][lane] = (unsigned short)cnt;
    pc2[wave][lane] = (unsigned short)cnt2;
    __syncthreads();

    if (wave == 0) {
        int r = 0, p = 0;
#pragma unroll
        for (int pp = 0; pp < 16; ++pp) { r += pc[pp][lane]; p += pc2[pp][lane]; }
        q_sorted[b * N + r] = ord2f(qj);
        p_arr[b * N + j] = p;
        rs[lane] = (unsigned short)r;
    }
    __syncthreads();

    // permute x into sorted order: 4 rows per wave, coalesced 256B each
#pragma unroll
    for (int s = 0; s < 4; ++s) {
        int jl = wave * 4 + s;
        int r = rs[jl];
        xs[((size_t)(b * N + r)) * F + lane] =
            x[((size_t)(b * N + jbase + jl)) * F + lane];
    }
}

// ---------------------------------------------------------------------------
// K3: fused chunk totals + intra-superchunk scans.
// grid BZ*64 (block = superchunk of 64 sorted rows) x 1024 (wave = subchunk).
// Writes: sub1 = excl SUFFIX over subchunks within super (of e^{d} sums)
//         sub2 = excl PREFIX over subchunks within super (of e^{0.2d} sums)
//         sup1/sup2 = full superchunk totals (scanned by out_kernel).
// ---------------------------------------------------------------------------
__global__ __launch_bounds__(1024) void chunkscan_kernel(
        const float* __restrict__ xs, const float* __restrict__ q_sorted,
        float* __restrict__ sub1, float* __restrict__ sub2,
        float* __restrict__ sup1, float* __restrict__ sup2) {
    __shared__ float l1[16][66], l2[16][66];
    int b = blockIdx.x >> 6;
    int sp = blockIdx.x & 63;
    int w = threadIdx.x >> 6, lane = threadIdx.x & 63;
    const float* qsb = q_sorted + b * N;
    float Qmax = qsb[N - 1];
    int base = sp * 64 + w * 4;               // sorted-row base of this sub
    float a1 = 0.f, a2 = 0.f, s1 = 0.f, s2 = 0.f;
#pragma unroll
    for (int r = 0; r < 4; ++r) {
        int t = base + r;
        float d = qsb[t] - Qmax;
        float e1 = __expf(d);
        float e2 = __expf(0.2f * d);
        float xv = xs[((size_t)(b * N + t)) * F + lane];
        a1 += e1 * xv; s1 += e1;
        a2 += e2 * xv; s2 += e2;
    }
    l1[w][lane] = a1; l2[w][lane] = a2;
    if (lane == 0) { l1[w][64] = s1; l2[w][64] = s2; }
    __syncthreads();

    float suf = 0.f, sufd = 0.f;
    for (int u = w + 1; u < 16; ++u) { suf += l1[u][lane]; sufd += l1[u][64]; }
    float pre = 0.f, pred = 0.f;
    for (int u = 0; u < w; ++u) { pre += l2[u][lane]; pred += l2[u][64]; }

    size_t srow = ((size_t)((b * 64 + sp) * 16 + w)) * NC;
    sub1[srow + lane] = suf;
    sub2[srow + lane] = pre;
    if (lane == 0) { sub1[srow + 64] = sufd; sub2[srow + 64] = pred; }

    size_t prow = ((size_t)(b * 64 + sp)) * NC;
    if (w == 0) {                              // suf over u>0 + own = total
        sup1[prow + lane] = suf + a1;
        if (lane == 0) sup1[prow + 64] = sufd + s1;
    }
    if (w == 15) {                             // pre over u<15 + own = total
        sup2[prow + lane] = pre + a2;
        if (lane == 0) sup2[prow + 64] = pred + s2;
    }
}

// ---------------------------------------------------------------------------
// K4: epilogue. grid BZ*64 x 1024 (16 waves x 4 rows).
// Loads 64 super-totals, scans them with wave shuffle scans (lane = super-
// chunk, 130 comp-jobs over 16 waves), then per row i:
//   p; c=min(p>>2,1023); sp=c>>4; su=c&15; r0=p-4c
//   a = superscan[sp] + subscan[sp][su] + tail(4 xs rows, split at r0)
// LDS transpose -> coalesced out[b][f][i].
// ---------------------------------------------------------------------------
__global__ __launch_bounds__(1024) void out_kernel(
        const float* __restrict__ karr, const float* __restrict__ q_sorted,
        const int* __restrict__ p_arr, const float* __restrict__ sub1,
        const float* __restrict__ sub2, const float* __restrict__ sup1,
        const float* __restrict__ sup2, const float* __restrict__ xs,
        float* __restrict__ out) {
    __shared__ float sS1[64][66], sS2[64][66];   // 33.8 KB
    __shared__ float tile[64 * 65];              // 16.6 KB
    int b = blockIdx.x >> 6;
    int i0 = (blockIdx.x & 63) * 64;
    int tid = threadIdx.x;
    int wave = tid >> 6, lane = tid & 63;
    const float* qsb = q_sorted + b * N;
    float Qmax = qsb[N - 1];

    // load super totals (64 rows x 65 comps x 2 arrays)
    for (int s = wave; s < 64; s += 16) {
        size_t prow = ((size_t)(b * 64 + s)) * NC;
        sS1[s][lane] = sup1[prow + lane];
        sS2[s][lane] = sup2[prow + lane];
        if (lane == 0) { sS1[s][64] = sup1[prow + 64]; sS2[s][64] = sup2[prow + 64]; }
    }
    __syncthreads();
    // wave shuffle scans: lane = superchunk s; job = comp (arr1) or 65+comp
    // (arr2). arr1: exclusive SUFFIX; arr2: exclusive PREFIX.
    for (int job = wave; job < 130; job += 16) {
        if (job < 65) {
            int comp = job;
            float v = sS1[lane][comp];
            float inc = v;
#pragma unroll
            for (int off = 1; off < 64; off <<= 1) {
                float o = __shfl_down(inc, off, 64);
                if (lane + off < 64) inc += o;
            }
            sS1[lane][comp] = inc - v;        // exclusive suffix
        } else {
            int comp = job - 65;
            float v = sS2[lane][comp];
            float inc = v;
#pragma unroll
            for (int off = 1; off < 64; off <<= 1) {
                float o = __shfl_up(inc, off, 64);
                if (lane >= off) inc += o;
            }
            sS2[lane][comp] = inc - v;        // exclusive prefix
        }
    }
    __syncthreads();

#pragma unroll
    for (int s = 0; s < 4; ++s) {
        int il = wave * 4 + s;
        int i = i0 + il;
        float kk = karr[b * N + i];
        int p = p_arr[b * N + i];
        int c = p >> 2; if (c > 1023) c = 1023;
        int sp = c >> 4, su = c & 15;
        int r0 = p - (c << 2);
        float u = kk + Qmax;
        float M = fmaxf(u, 0.2f * u);
        float c1 = __expf(u - M);
        float c2 = __expf(0.2f * u - M);
        size_t srow = ((size_t)((b * 64 + sp) * 16 + su)) * NC;
        float a1 = sS1[sp][lane] + sub1[srow + lane];
        float s1 = sS1[sp][64] + sub1[srow + 64];
        float a2 = sS2[sp][lane] + sub2[srow + lane];
        float s2 = sS2[sp][64] + sub2[srow + 64];
        int tb = c << 2;
#pragma unroll
        for (int r = 0; r < 4; ++r) {
            float d = qsb[tb + r] - Qmax;
            float xv = xs[((size_t)(b * N + tb + r)) * F + lane];
            if (r >= r0) { float e1 = __expf(d);        a1 += e1 * xv; s1 += e1; }
            else         { float e2 = __expf(0.2f * d); a2 += e2 * xv; s2 += e2; }
        }
        float num = c1 * a1 + c2 * a2;
        float den = c1 * s1 + c2 * s2;
        tile[lane * 65 + il] = num / den;
    }
    __syncthreads();
#pragma unroll
    for (int rep = 0; rep < 4; ++rep) {
        int ff = rep * 16 + wave;
        out[((size_t)(b * F + ff)) * N + i0 + lane] = tile[ff * 65 + lane];
    }
}

// ---------------------------------------------------------------------------
extern "C" void kernel_launch(void* const* d_in, const int* in_sizes, int n_in,
                              void* d_out, int out_size, void* d_ws, size_t ws_size,
                              hipStream_t stream) {
    const float* x  = (const float*)d_in[0];
    const float* wk = (const float*)d_in[1];
    const float* wq = (const float*)d_in[2];
    float* out = (float*)d_out;

    // ws layout (floats): karr[BZ*N] | qord(u32)[BZ*N] | q_sorted[BZ*N] |
    //   p_arr[BZ*N] | sub1[BZ*1024*NC] | sub2[...] | sup1[BZ*64*NC] |
    //   sup2[...] | xs[BZ*N*F]
    float* ws = (float*)d_ws;
    float* karr = ws;
    unsigned int* qord = (unsigned int*)(ws + BZ * N);
    float* q_sorted = ws + 2 * BZ * N;
    int*   p_arr    = (int*)(ws + 3 * BZ * N);
    float* sub1     = ws + 4 * BZ * N;
    float* sub2     = sub1 + (size_t)BZ * 1024 * NC;
    float* sup1     = sub2 + (size_t)BZ * 1024 * NC;
    float* sup2     = sup1 + (size_t)BZ * 64 * NC;
    float* xs       = sup2 + (size_t)BZ * 64 * NC;

    kq_kernel<<<BZ * N / 4, 256, 0, stream>>>(x, wk, wq, karr, qord);
    rank_kernel<<<BZ * 64, 1024, 0, stream>>>(x, karr, qord, q_sorted, p_arr, xs);
    chunkscan_kernel<<<BZ * 64, 1024, 0, stream>>>(xs, q_sorted, sub1, sub2,
                                                   sup1, sup2);
    out_kernel<<<BZ * 64, 1024, 0, stream>>>(karr, q_sorted, p_arr, sub1, sub2,
                                             sup1, sup2, xs, out);
}

// Round 8
// 93.487 us; speedup vs baseline: 1.1056x; 1.1056x over previous
//
#include <hip/hip_runtime.h>

#define N 4096
#define F 64
#define BZ 4
#define NC 65            // 64 features + 1 denominator component
// hierarchy: 64 superchunks x 16 subchunks x 4 rows = 4096 sorted rows

// order-preserving float <-> uint32 mapping
__device__ __forceinline__ unsigned int f2ord(float f) {
    unsigned int u = __float_as_uint(f);
    return (u & 0x80000000u) ? ~u : (u ^ 0x80000000u);
}
__device__ __forceinline__ float ord2f(unsigned int v) {
    unsigned int b = (v & 0x80000000u) ? (v ^ 0x80000000u) : ~v;
    return __uint_as_float(b);
}

// ---------------------------------------------------------------------------
// K1: karr[b][i] = x·wk (float); qkey[b][i] = (ord(x·wq)<<32)|i. Wave per row.
// ---------------------------------------------------------------------------
__global__ __launch_bounds__(256) void kq_kernel(
        const float* __restrict__ x, const float* __restrict__ wk,
        const float* __restrict__ wq, float* __restrict__ karr,
        unsigned long long* __restrict__ qkey) {
    int wave = blockIdx.x * 4 + (threadIdx.x >> 6);
    int lane = threadIdx.x & 63;
    int row = wave;                     // 0..BZ*N-1
    float xv = x[(size_t)row * F + lane];
    float kk = xv * wk[lane];
    float qq = xv * wq[lane];
    for (int off = 32; off > 0; off >>= 1) {
        kk += __shfl_down(kk, off, 64);
        qq += __shfl_down(qq, off, 64);
    }
    if (lane == 0) {
        karr[row] = kk;
        qkey[row] = ((unsigned long long)f2ord(qq) << 32)
                  | (unsigned int)(row & (N - 1));
    }
}

// ---------------------------------------------------------------------------
// K2: counting rank-sort on u64 keys + split points + x permutation.
// grid BZ*64 x 1024. Wave-uniform (broadcast) LDS reads; 1-inst u64 compares.
//   rank_j = #{s : key_s < key_j}        (strict total order, exact)
//   p_j    = #{s : ord(q_s) < ord(-k_j)} (tie direction irrelevant: e^0 both)
// ---------------------------------------------------------------------------
__global__ __launch_bounds__(1024) void rank_kernel(
        const float* __restrict__ x, const float* __restrict__ karr,
        const unsigned long long* __restrict__ qkey,
        float* __restrict__ q_sorted, int* __restrict__ p_arr,
        float* __restrict__ xs) {
    __shared__ __align__(16) unsigned long long qs[N];   // 32 KB
    __shared__ unsigned short pc[16][64];
    __shared__ unsigned short pc2[16][64];
    __shared__ unsigned short rs[64];
    int b = blockIdx.x >> 6;
    int tid = threadIdx.x;
    int wave = tid >> 6, lane = tid & 63;
    const unsigned long long* qb = qkey + b * N;
    for (int t = tid; t < N; t += 1024) qs[t] = qb[t];
    __syncthreads();

    int jbase = (blockIdx.x & 63) * 64;
    int j = jbase + lane;
    unsigned long long myKey = qs[j];
    unsigned int thOu = f2ord(-karr[b * N + j]);
    int cnt = 0, cnt2 = 0;
    const ulonglong2* q2 = (const ulonglong2*)qs;
    int s0 = wave * 128;                      // ulonglong2 units
#pragma unroll 8
    for (int t2 = 0; t2 < 128; ++t2) {
        ulonglong2 v = q2[s0 + t2];
        cnt  += (int)(v.x < myKey) + (int)(v.y < myKey);
        cnt2 += (int)((unsigned int)(v.x >> 32) < thOu)
              + (int)((unsigned int)(v.y >> 32) < thOu);
    }
    pc[wave][lane] = (unsigned short)cnt;
    pc2[wave][lane] = (unsigned short)cnt2;
    __syncthreads();

    if (wave == 0) {
        int r = 0, p = 0;
#pragma unroll
        for (int pp = 0; pp < 16; ++pp) { r += pc[pp][lane]; p += pc2[pp][lane]; }
        q_sorted[b * N + r] = ord2f((unsigned int)(myKey >> 32));
        p_arr[b * N + j] = p;
        rs[lane] = (unsigned short)r;
    }
    __syncthreads();

    // permute x into sorted order: 4 rows per wave, coalesced 256B each
#pragma unroll
    for (int s = 0; s < 4; ++s) {
        int jl = wave * 4 + s;
        int r = rs[jl];
        xs[((size_t)(b * N + r)) * F + lane] =
            x[((size_t)(b * N + jbase + jl)) * F + lane];
    }
}

// ---------------------------------------------------------------------------
// K3: fused chunk totals + intra-superchunk scans.
// grid BZ*64 (block = superchunk of 64 sorted rows) x 1024 (wave = subchunk).
// Writes: sub1 = excl SUFFIX over subchunks within super (of e^{d} sums)
//         sub2 = excl PREFIX over subchunks within super (of e^{0.2d} sums)
//         sup1/sup2 = full superchunk totals (scanned by out_kernel).
// ---------------------------------------------------------------------------
__global__ __launch_bounds__(1024) void chunkscan_kernel(
        const float* __restrict__ xs, const float* __restrict__ q_sorted,
        float* __restrict__ sub1, float* __restrict__ sub2,
        float* __restrict__ sup1, float* __restrict__ sup2) {
    __shared__ float l1[16][66], l2[16][66];
    int b = blockIdx.x >> 6;
    int sp = blockIdx.x & 63;
    int w = threadIdx.x >> 6, lane = threadIdx.x & 63;
    const float* qsb = q_sorted + b * N;
    float Qmax = qsb[N - 1];
    int base = sp * 64 + w * 4;               // sorted-row base of this sub
    float a1 = 0.f, a2 = 0.f, s1 = 0.f, s2 = 0.f;
#pragma unroll
    for (int r = 0; r < 4; ++r) {
        int t = base + r;
        float d = qsb[t] - Qmax;
        float e1 = __expf(d);
        float e2 = __expf(0.2f * d);
        float xv = xs[((size_t)(b * N + t)) * F + lane];
        a1 += e1 * xv; s1 += e1;
        a2 += e2 * xv; s2 += e2;
    }
    l1[w][lane] = a1; l2[w][lane] = a2;
    if (lane == 0) { l1[w][64] = s1; l2[w][64] = s2; }
    __syncthreads();

    float suf = 0.f, sufd = 0.f;
    for (int u = w + 1; u < 16; ++u) { suf += l1[u][lane]; sufd += l1[u][64]; }
    float pre = 0.f, pred = 0.f;
    for (int u = 0; u < w; ++u) { pre += l2[u][lane]; pred += l2[u][64]; }

    size_t srow = ((size_t)((b * 64 + sp) * 16 + w)) * NC;
    sub1[srow + lane] = suf;
    sub2[srow + lane] = pre;
    if (lane == 0) { sub1[srow + 64] = sufd; sub2[srow + 64] = pred; }

    size_t prow = ((size_t)(b * 64 + sp)) * NC;
    if (w == 0) {                              // suf over u>0 + own = total
        sup1[prow + lane] = suf + a1;
        if (lane == 0) sup1[prow + 64] = sufd + s1;
    }
    if (w == 15) {                             // pre over u<15 + own = total
        sup2[prow + lane] = pre + a2;
        if (lane == 0) sup2[prow + 64] = pred + s2;
    }
}

// ---------------------------------------------------------------------------
// K4: epilogue. grid BZ*64 x 1024 (16 waves x 4 rows).
// Loads 64 super-totals, scans them in LDS with a SEGMENTED two-pass scan
// (4 independent 16-chains for ILP instead of one 64-dep chain), then per i:
//   p; c=min(p>>2,1023); sp=c>>4; su=c&15; r0=p-4c
//   a = superscan[sp] + subscan[sp][su] + tail(4 xs rows, split at r0)
// LDS transpose -> coalesced out[b][f][i].
// ---------------------------------------------------------------------------
__global__ __launch_bounds__(1024) void out_kernel(
        const float* __restrict__ karr, const float* __restrict__ q_sorted,
        const int* __restrict__ p_arr, const float* __restrict__ sub1,
        const float* __restrict__ sub2, const float* __restrict__ sup1,
        const float* __restrict__ sup2, const float* __restrict__ xs,
        float* __restrict__ out) {
    __shared__ float sS1[64][66], sS2[64][66];   // 33.8 KB
    __shared__ float tile[64 * 65];              // 16.6 KB
    int b = blockIdx.x >> 6;
    int i0 = (blockIdx.x & 63) * 64;
    int tid = threadIdx.x;
    int wave = tid >> 6, lane = tid & 63;
    const float* qsb = q_sorted + b * N;
    float Qmax = qsb[N - 1];

    // load super totals (64 rows x 65 comps x 2 arrays)
    for (int s = wave; s < 64; s += 16) {
        size_t prow = ((size_t)(b * 64 + s)) * NC;
        sS1[s][lane] = sup1[prow + lane];
        sS2[s][lane] = sup2[prow + lane];
        if (lane == 0) { sS1[s][64] = sup1[prow + 64]; sS2[s][64] = sup2[prow + 64]; }
    }
    __syncthreads();
    // segmented scans: thread = comp. arr1 excl SUFFIX, arr2 excl PREFIX.
    // pass 1: four independent 16-elem segment sums (ILP); pass 2: four
    // interleaved 16-step rewrites from per-segment exclusive bases.
    if (tid < 65) {
        int comp = tid;
        float g0 = 0.f, g1 = 0.f, g2 = 0.f, g3 = 0.f;
#pragma unroll
        for (int e = 0; e < 16; ++e) {
            g0 += sS1[e][comp];      g1 += sS1[16 + e][comp];
            g2 += sS1[32 + e][comp]; g3 += sS1[48 + e][comp];
        }
        // exclusive suffix bases per segment
        float r0 = g1 + g2 + g3, r1 = g2 + g3, r2 = g3, r3 = 0.f;
#pragma unroll
        for (int e = 15; e >= 0; --e) {
            float v0 = sS1[e][comp],      v1 = sS1[16 + e][comp];
            float v2 = sS1[32 + e][comp], v3 = sS1[48 + e][comp];
            sS1[e][comp] = r0;      r0 += v0;
            sS1[16 + e][comp] = r1; r1 += v1;
            sS1[32 + e][comp] = r2; r2 += v2;
            sS1[48 + e][comp] = r3; r3 += v3;
        }
    } else if (tid < 130) {
        int comp = tid - 65;
        float g0 = 0.f, g1 = 0.f, g2 = 0.f, g3 = 0.f;
#pragma unroll
        for (int e = 0; e < 16; ++e) {
            g0 += sS2[e][comp];      g1 += sS2[16 + e][comp];
            g2 += sS2[32 + e][comp]; g3 += sS2[48 + e][comp];
        }
        // exclusive prefix bases per segment
        float r0 = 0.f, r1 = g0, r2 = g0 + g1, r3 = g0 + g1 + g2;
#pragma unroll
        for (int e = 0; e < 16; ++e) {
            float v0 = sS2[e][comp],      v1 = sS2[16 + e][comp];
            float v2 = sS2[32 + e][comp], v3 = sS2[48 + e][comp];
            sS2[e][comp] = r0;      r0 += v0;
            sS2[16 + e][comp] = r1; r1 += v1;
            sS2[32 + e][comp] = r2; r2 += v2;
            sS2[48 + e][comp] = r3; r3 += v3;
        }
    }
    __syncthreads();

#pragma unroll
    for (int s = 0; s < 4; ++s) {
        int il = wave * 4 + s;
        int i = i0 + il;
        float kk = karr[b * N + i];
        int p = p_arr[b * N + i];
        int c = p >> 2; if (c > 1023) c = 1023;
        int sp = c >> 4, su = c & 15;
        int r0 = p - (c << 2);
        float u = kk + Qmax;
        float M = fmaxf(u, 0.2f * u);
        float c1 = __expf(u - M);
        float c2 = __expf(0.2f * u - M);
        size_t srow = ((size_t)((b * 64 + sp) * 16 + su)) * NC;
        float a1 = sS1[sp][lane] + sub1[srow + lane];
        float s1 = sS1[sp][64] + sub1[srow + 64];
        float a2 = sS2[sp][lane] + sub2[srow + lane];
        float s2 = sS2[sp][64] + sub2[srow + 64];
        int tb = c << 2;
#pragma unroll
        for (int r = 0; r < 4; ++r) {
            float d = qsb[tb + r] - Qmax;
            float xv = xs[((size_t)(b * N + tb + r)) * F + lane];
            if (r >= r0) { float e1 = __expf(d);        a1 += e1 * xv; s1 += e1; }
            else         { float e2 = __expf(0.2f * d); a2 += e2 * xv; s2 += e2; }
        }
        float num = c1 * a1 + c2 * a2;
        float den = c1 * s1 + c2 * s2;
        tile[lane * 65 + il] = num / den;
    }
    __syncthreads();
#pragma unroll
    for (int rep = 0; rep < 4; ++rep) {
        int ff = rep * 16 + wave;
        out[((size_t)(b * F + ff)) * N + i0 + lane] = tile[ff * 65 + lane];
    }
}

// ---------------------------------------------------------------------------
extern "C" void kernel_launch(void* const* d_in, const int* in_sizes, int n_in,
                              void* d_out, int out_size, void* d_ws, size_t ws_size,
                              hipStream_t stream) {
    const float* x  = (const float*)d_in[0];
    const float* wk = (const float*)d_in[1];
    const float* wq = (const float*)d_in[2];
    float* out = (float*)d_out;

    // ws layout (floats): karr[BZ*N] | qkey(u64)[BZ*N] (=2*BZ*N floats) |
    //   q_sorted[BZ*N] | p_arr[BZ*N] | sub1[BZ*1024*NC] | sub2[...] |
    //   sup1[BZ*64*NC] | sup2[...] | xs[BZ*N*F]
    float* ws = (float*)d_ws;
    float* karr = ws;
    unsigned long long* qkey = (unsigned long long*)(ws + BZ * N);
    float* q_sorted = ws + 3 * BZ * N;
    int*   p_arr    = (int*)(ws + 4 * BZ * N);
    float* sub1     = ws + 5 * BZ * N;
    float* sub2     = sub1 + (size_t)BZ * 1024 * NC;
    float* sup1     = sub2 + (size_t)BZ * 1024 * NC;
    float* sup2     = sup1 + (size_t)BZ * 64 * NC;
    float* xs       = sup2 + (size_t)BZ * 64 * NC;

    kq_kernel<<<BZ * N / 4, 256, 0, stream>>>(x, wk, wq, karr, qkey);
    rank_kernel<<<BZ * 64, 1024, 0, stream>>>(x, karr, qkey, q_sorted, p_arr, xs);
    chunkscan_kernel<<<BZ * 64, 1024, 0, stream>>>(xs, q_sorted, sub1, sub2,
                                                   sup1, sup2);
    out_kernel<<<BZ * 64, 1024, 0, stream>>>(karr, q_sorted, p_arr, sub1, sub2,
                                             sup1, sup2, xs, out);
}

// Round 9
// 90.286 us; speedup vs baseline: 1.1448x; 1.0355x over previous
//
#include <hip/hip_runtime.h>

#define N 4096
#define F 64
#define BZ 4
#define NC 65            // 64 features + 1 denominator component
// hierarchy: 64 superchunks x 16 subchunks x 4 rows = 4096 sorted rows

// order-preserving float <-> uint32 mapping
__device__ __forceinline__ unsigned int f2ord(float f) {
    unsigned int u = __float_as_uint(f);
    return (u & 0x80000000u) ? ~u : (u ^ 0x80000000u);
}
__device__ __forceinline__ float ord2f(unsigned int v) {
    unsigned int b = (v & 0x80000000u) ? (v ^ 0x80000000u) : ~v;
    return __uint_as_float(b);
}

// ---------------------------------------------------------------------------
// K1: karr[b][i] = x·wk (float); qkey[b][i] = (ord(x·wq)<<32)|i. Wave per row.
// ---------------------------------------------------------------------------
__global__ __launch_bounds__(256) void kq_kernel(
        const float* __restrict__ x, const float* __restrict__ wk,
        const float* __restrict__ wq, float* __restrict__ karr,
        unsigned long long* __restrict__ qkey) {
    int wave = blockIdx.x * 4 + (threadIdx.x >> 6);
    int lane = threadIdx.x & 63;
    int row = wave;                     // 0..BZ*N-1
    float xv = x[(size_t)row * F + lane];
    float kk = xv * wk[lane];
    float qq = xv * wq[lane];
    for (int off = 32; off > 0; off >>= 1) {
        kk += __shfl_down(kk, off, 64);
        qq += __shfl_down(qq, off, 64);
    }
    if (lane == 0) {
        karr[row] = kk;
        qkey[row] = ((unsigned long long)f2ord(qq) << 32)
                  | (unsigned int)(row & (N - 1));
    }
}

// ---------------------------------------------------------------------------
// K2: counting rank-sort on u64 keys + x permutation. grid BZ*64 x 1024.
// Broadcast (wave-uniform) LDS reads return 16B/inst -> VALU-bound; inner
// loop is now ONLY the rank count (2 ops/elem). p moved to out_kernel.
//   rank_j = #{s : key_s < key_j}        (strict total order, exact)
// ---------------------------------------------------------------------------
__global__ __launch_bounds__(1024) void rank_kernel(
        const float* __restrict__ x,
        const unsigned long long* __restrict__ qkey,
        float* __restrict__ q_sorted, float* __restrict__ xs) {
    __shared__ __align__(16) unsigned long long qs[N];   // 32 KB
    __shared__ unsigned short pc[16][64];
    __shared__ unsigned short rs[64];
    int b = blockIdx.x >> 6;
    int tid = threadIdx.x;
    int wave = tid >> 6, lane = tid & 63;
    const unsigned long long* qb = qkey + b * N;
    for (int t = tid; t < N; t += 1024) qs[t] = qb[t];
    __syncthreads();

    int jbase = (blockIdx.x & 63) * 64;
    int j = jbase + lane;
    unsigned long long myKey = qs[j];
    int cnt = 0;
    const ulonglong2* q2 = (const ulonglong2*)qs;
    int s0 = wave * 128;                      // ulonglong2 units
#pragma unroll 8
    for (int t2 = 0; t2 < 128; ++t2) {
        ulonglong2 v = q2[s0 + t2];
        cnt += (int)(v.x < myKey) + (int)(v.y < myKey);
    }
    pc[wave][lane] = (unsigned short)cnt;
    __syncthreads();

    if (wave == 0) {
        int r = 0;
#pragma unroll
        for (int pp = 0; pp < 16; ++pp) r += pc[pp][lane];
        q_sorted[b * N + r] = ord2f((unsigned int)(myKey >> 32));
        rs[lane] = (unsigned short)r;
    }
    __syncthreads();

    // permute x into sorted order: 4 rows per wave, coalesced 256B each
#pragma unroll
    for (int s = 0; s < 4; ++s) {
        int jl = wave * 4 + s;
        int r = rs[jl];
        xs[((size_t)(b * N + r)) * F + lane] =
            x[((size_t)(b * N + jbase + jl)) * F + lane];
    }
}

// ---------------------------------------------------------------------------
// K3: fused chunk totals + intra-superchunk scans.
// grid BZ*64 (block = superchunk of 64 sorted rows) x 1024 (wave = subchunk).
// Writes: sub1 = excl SUFFIX over subchunks within super (of e^{d} sums)
//         sub2 = excl PREFIX over subchunks within super (of e^{0.2d} sums)
//         sup1/sup2 = full superchunk totals (scanned by out_kernel).
// ---------------------------------------------------------------------------
__global__ __launch_bounds__(1024) void chunkscan_kernel(
        const float* __restrict__ xs, const float* __restrict__ q_sorted,
        float* __restrict__ sub1, float* __restrict__ sub2,
        float* __restrict__ sup1, float* __restrict__ sup2) {
    __shared__ float l1[16][66], l2[16][66];
    int b = blockIdx.x >> 6;
    int sp = blockIdx.x & 63;
    int w = threadIdx.x >> 6, lane = threadIdx.x & 63;
    const float* qsb = q_sorted + b * N;
    float Qmax = qsb[N - 1];
    int base = sp * 64 + w * 4;               // sorted-row base of this sub
    float a1 = 0.f, a2 = 0.f, s1 = 0.f, s2 = 0.f;
#pragma unroll
    for (int r = 0; r < 4; ++r) {
        int t = base + r;
        float d = qsb[t] - Qmax;
        float e1 = __expf(d);
        float e2 = __expf(0.2f * d);
        float xv = xs[((size_t)(b * N + t)) * F + lane];
        a1 += e1 * xv; s1 += e1;
        a2 += e2 * xv; s2 += e2;
    }
    l1[w][lane] = a1; l2[w][lane] = a2;
    if (lane == 0) { l1[w][64] = s1; l2[w][64] = s2; }
    __syncthreads();

    float suf = 0.f, sufd = 0.f;
    for (int u = w + 1; u < 16; ++u) { suf += l1[u][lane]; sufd += l1[u][64]; }
    float pre = 0.f, pred = 0.f;
    for (int u = 0; u < w; ++u) { pre += l2[u][lane]; pred += l2[u][64]; }

    size_t srow = ((size_t)((b * 64 + sp) * 16 + w)) * NC;
    sub1[srow + lane] = suf;
    sub2[srow + lane] = pre;
    if (lane == 0) { sub1[srow + 64] = sufd; sub2[srow + 64] = pred; }

    size_t prow = ((size_t)(b * 64 + sp)) * NC;
    if (w == 0) {                              // suf over u>0 + own = total
        sup1[prow + lane] = suf + a1;
        if (lane == 0) sup1[prow + 64] = sufd + s1;
    }
    if (w == 15) {                             // pre over u<15 + own = total
        sup2[prow + lane] = pre + a2;
        if (lane == 0) sup2[prow + 64] = pred + s2;
    }
}

// ---------------------------------------------------------------------------
// K4: epilogue. grid BZ*64 x 1024 (16 waves x 4 rows).
// Concurrent setup phase: threads 0..129 scan super-totals in LDS (segmented
// 4x16 two-pass), threads 130..193 binary-search p_i = lower_bound(q_sorted,
// -k_i) for the block's 64 rows (tie direction weight-neutral: k+q=0 -> e^0).
// Then per row i: c=min(p>>2,1023); sp=c>>4; su=c&15; r0=p-4c;
//   a = superscan[sp] + subscan[sp][su] + tail(4 xs rows, split at r0)
// LDS transpose -> coalesced out[b][f][i].
// ---------------------------------------------------------------------------
__global__ __launch_bounds__(1024) void out_kernel(
        const float* __restrict__ karr, const float* __restrict__ q_sorted,
        const float* __restrict__ sub1, const float* __restrict__ sub2,
        const float* __restrict__ sup1, const float* __restrict__ sup2,
        const float* __restrict__ xs, float* __restrict__ out) {
    __shared__ float sS1[64][66], sS2[64][66];   // 33.8 KB
    __shared__ float tile[64 * 65];              // 16.6 KB
    __shared__ int pA[64];
    __shared__ float kkA[64];
    int b = blockIdx.x >> 6;
    int i0 = (blockIdx.x & 63) * 64;
    int tid = threadIdx.x;
    int wave = tid >> 6, lane = tid & 63;
    const float* qsb = q_sorted + b * N;
    float Qmax = qsb[N - 1];

    // load super totals (64 rows x 65 comps x 2 arrays)
    for (int s = wave; s < 64; s += 16) {
        size_t prow = ((size_t)(b * 64 + s)) * NC;
        sS1[s][lane] = sup1[prow + lane];
        sS2[s][lane] = sup2[prow + lane];
        if (lane == 0) { sS1[s][64] = sup1[prow + 64]; sS2[s][64] = sup2[prow + 64]; }
    }
    __syncthreads();
    // threads 0..64: arr1 excl SUFFIX scan; 65..129: arr2 excl PREFIX scan;
    // 130..193: binary search p for rows 0..63 (independent of LDS supers).
    if (tid < 65) {
        int comp = tid;
        float g0 = 0.f, g1 = 0.f, g2 = 0.f, g3 = 0.f;
#pragma unroll
        for (int e = 0; e < 16; ++e) {
            g0 += sS1[e][comp];      g1 += sS1[16 + e][comp];
            g2 += sS1[32 + e][comp]; g3 += sS1[48 + e][comp];
        }
        float r0 = g1 + g2 + g3, r1 = g2 + g3, r2 = g3, r3 = 0.f;
#pragma unroll
        for (int e = 15; e >= 0; --e) {
            float v0 = sS1[e][comp],      v1 = sS1[16 + e][comp];
            float v2 = sS1[32 + e][comp], v3 = sS1[48 + e][comp];
            sS1[e][comp] = r0;      r0 += v0;
            sS1[16 + e][comp] = r1; r1 += v1;
            sS1[32 + e][comp] = r2; r2 += v2;
            sS1[48 + e][comp] = r3; r3 += v3;
        }
    } else if (tid < 130) {
        int comp = tid - 65;
        float g0 = 0.f, g1 = 0.f, g2 = 0.f, g3 = 0.f;
#pragma unroll
        for (int e = 0; e < 16; ++e) {
            g0 += sS2[e][comp];      g1 += sS2[16 + e][comp];
            g2 += sS2[32 + e][comp]; g3 += sS2[48 + e][comp];
        }
        float r0 = 0.f, r1 = g0, r2 = g0 + g1, r3 = g0 + g1 + g2;
#pragma unroll
        for (int e = 0; e < 16; ++e) {
            float v0 = sS2[e][comp],      v1 = sS2[16 + e][comp];
            float v2 = sS2[32 + e][comp], v3 = sS2[48 + e][comp];
            sS2[e][comp] = r0;      r0 += v0;
            sS2[16 + e][comp] = r1; r1 += v1;
            sS2[32 + e][comp] = r2; r2 += v2;
            sS2[48 + e][comp] = r3; r3 += v3;
        }
    } else if (tid < 194) {
        int il = tid - 130;
        float kk = karr[b * N + i0 + il];
        float theta = -kk;
        int lo = 0, hi = N;
#pragma unroll
        for (int step = 0; step < 12; ++step) {
            int mid = (lo + hi) >> 1;
            if (qsb[mid] < theta) lo = mid + 1; else hi = mid;
        }
        pA[il] = lo;
        kkA[il] = kk;
    }
    __syncthreads();

#pragma unroll
    for (int s = 0; s < 4; ++s) {
        int il = wave * 4 + s;
        float kk = kkA[il];
        int p = pA[il];
        int c = p >> 2; if (c > 1023) c = 1023;
        int sp = c >> 4, su = c & 15;
        int r0 = p - (c << 2);
        float u = kk + Qmax;
        float M = fmaxf(u, 0.2f * u);
        float c1 = __expf(u - M);
        float c2 = __expf(0.2f * u - M);
        size_t srow = ((size_t)((b * 64 + sp) * 16 + su)) * NC;
        float a1 = sS1[sp][lane] + sub1[srow + lane];
        float s1 = sS1[sp][64] + sub1[srow + 64];
        float a2 = sS2[sp][lane] + sub2[srow + lane];
        float s2 = sS2[sp][64] + sub2[srow + 64];
        int tb = c << 2;
#pragma unroll
        for (int r = 0; r < 4; ++r) {
            float d = qsb[tb + r] - Qmax;
            float xv = xs[((size_t)(b * N + tb + r)) * F + lane];
            if (r >= r0) { float e1 = __expf(d);        a1 += e1 * xv; s1 += e1; }
            else         { float e2 = __expf(0.2f * d); a2 += e2 * xv; s2 += e2; }
        }
        float num = c1 * a1 + c2 * a2;
        float den = c1 * s1 + c2 * s2;
        tile[lane * 65 + il] = num / den;
    }
    __syncthreads();
#pragma unroll
    for (int rep = 0; rep < 4; ++rep) {
        int ff = rep * 16 + wave;
        out[((size_t)(b * F + ff)) * N + i0 + lane] = tile[ff * 65 + lane];
    }
}

// ---------------------------------------------------------------------------
extern "C" void kernel_launch(void* const* d_in, const int* in_sizes, int n_in,
                              void* d_out, int out_size, void* d_ws, size_t ws_size,
                              hipStream_t stream) {
    const float* x  = (const float*)d_in[0];
    const float* wk = (const float*)d_in[1];
    const float* wq = (const float*)d_in[2];
    float* out = (float*)d_out;

    // ws layout (floats): karr[BZ*N] | qkey(u64)[BZ*N] (=2*BZ*N floats) |
    //   q_sorted[BZ*N] | sub1[BZ*1024*NC] | sub2[...] | sup1[BZ*64*NC] |
    //   sup2[...] | xs[BZ*N*F]
    float* ws = (float*)d_ws;
    float* karr = ws;
    unsigned long long* qkey = (unsigned long long*)(ws + BZ * N);
    float* q_sorted = ws + 3 * BZ * N;
    float* sub1     = ws + 4 * BZ * N;
    float* sub2     = sub1 + (size_t)BZ * 1024 * NC;
    float* sup1     = sub2 + (size_t)BZ * 1024 * NC;
    float* sup2     = sup1 + (size_t)BZ * 64 * NC;
    float* xs       = sup2 + (size_t)BZ * 64 * NC;

    kq_kernel<<<BZ * N / 4, 256, 0, stream>>>(x, wk, wq, karr, qkey);
    rank_kernel<<<BZ * 64, 1024, 0, stream>>>(x, qkey, q_sorted, xs);
    chunkscan_kernel<<<BZ * 64, 1024, 0, stream>>>(xs, q_sorted, sub1, sub2,
                                                   sup1, sup2);
    out_kernel<<<BZ * 64, 1024, 0, stream>>>(karr, q_sorted, sub1, sub2,
                                             sup1, sup2, xs, out);
}